// Round 8
// baseline (197.638 us; speedup 1.0000x reference)
//
#include <hip/hip_runtime.h>

// REConv forward via dst-CSR gather. Zero scattered global atomics.
// Pipeline: hist -> reduce -> scan1/2/3 -> pboff -> transform -> bucket_lds -> gather.
//   - transform runs BEFORE bucket so bucket's sorted_src writes are the freshest
//     lines in each XCD's L2 when gather (XCD-affinity swizzled) reads them.
//   - gather: 2 edges per wave-load (lane = 2 features via u32 of 2xbf16;
//     lower 32 lanes = edge i, upper = edge i+1), 8-edge unroll, shfl_xor combine.
//   - NSLICE=32: partial = 12.8MB (halves reduce/pboff traffic); h16 separate.
//   - NT stores only on scalar types (NT builtins reject HIP_vector_type).
// F_IN = F_OUT = 64 hardcoded.

#define THREADS 256
#define SCAN_CHUNK 1024
#define NSLICE 32
#define MAXREG 12800   // bins per region cap; LDS = 51.2 KB

__device__ __forceinline__ unsigned f2bf(float f) {   // RTNE f32->bf16 bits
    unsigned x = __float_as_uint(f);
    return (x + 0x7fffu + ((x >> 16) & 1u)) >> 16;
}

__global__ void hist_kernel(const int* __restrict__ src, const int* __restrict__ dst,
                            unsigned int* __restrict__ partial,
                            int E, int nreg, int regsz, int chunk, int N) {
    __shared__ unsigned int hist[MAXREG];
    int r = blockIdx.x % nreg;
    int s = blockIdx.x / nreg;
    int lo = r * regsz;
    int hi = min(lo + regsz, N);
    int nb = hi - lo;
    int t = threadIdx.x;
    for (int b = t; b < nb; b += THREADS) hist[b] = 0u;
    __syncthreads();

    int ebeg = s * chunk;
    int eend = min(E, ebeg + chunk);
    int main_end = ebeg + ((eend - ebeg) & ~3);
    for (int i = ebeg + t * 4; i + 4 <= main_end; i += THREADS * 4) {
        int4 s4 = *(const int4*)(src + i);
        int4 d4 = *(const int4*)(dst + i);
        if (s4.x >= lo && s4.x < hi) atomicAdd(&hist[s4.x - lo], 1u);
        if (s4.y >= lo && s4.y < hi) atomicAdd(&hist[s4.y - lo], 1u);
        if (s4.z >= lo && s4.z < hi) atomicAdd(&hist[s4.z - lo], 1u);
        if (s4.w >= lo && s4.w < hi) atomicAdd(&hist[s4.w - lo], 1u);
        if (d4.x >= lo && d4.x < hi) atomicAdd(&hist[d4.x - lo], 65536u);
        if (d4.y >= lo && d4.y < hi) atomicAdd(&hist[d4.y - lo], 65536u);
        if (d4.z >= lo && d4.z < hi) atomicAdd(&hist[d4.z - lo], 65536u);
        if (d4.w >= lo && d4.w < hi) atomicAdd(&hist[d4.w - lo], 65536u);
    }
    for (int i = main_end + t; i < eend; i += THREADS) {
        int sv = src[i], dv = dst[i];
        if (sv >= lo && sv < hi) atomicAdd(&hist[sv - lo], 1u);
        if (dv >= lo && dv < hi) atomicAdd(&hist[dv - lo], 65536u);
    }
    __syncthreads();
    unsigned int* pp = partial + (size_t)blockIdx.x * regsz;
    for (int b = t; b < nb; b += THREADS) pp[b] = hist[b];
}

__global__ void reduce_kernel(const unsigned int* __restrict__ partial,
                              unsigned int* __restrict__ outdeg, unsigned int* __restrict__ indeg,
                              int N, int nreg, int regsz) {
    int bin = blockIdx.x * blockDim.x + threadIdx.x;
    if (bin >= N) return;
    int r = bin / regsz;
    int lbin = bin - r * regsz;
    unsigned int so = 0, si = 0;
    for (int s = 0; s < NSLICE; ++s) {
        unsigned int v = partial[(size_t)(s * nreg + r) * regsz + lbin];
        so += v & 0xffffu;
        si += v >> 16;
    }
    outdeg[bin] = so;
    indeg[bin] = si;
}

__global__ void scan1_kernel(const unsigned int* __restrict__ indeg,
                             unsigned int* __restrict__ offsets,
                             unsigned int* __restrict__ blockSums, int N) {
    __shared__ unsigned int sdata[256];
    int t = threadIdx.x;
    int base = blockIdx.x * SCAN_CHUNK;
    unsigned int v[4];
    unsigned int s = 0;
#pragma unroll
    for (int i = 0; i < 4; ++i) {
        int idx = base + t * 4 + i;
        v[i] = (idx < N) ? indeg[idx] : 0u;
        s += v[i];
    }
    sdata[t] = s;
    __syncthreads();
    for (int off = 1; off < 256; off <<= 1) {
        unsigned int x = (t >= off) ? sdata[t - off] : 0u;
        __syncthreads();
        sdata[t] += x;
        __syncthreads();
    }
    if (t == 255) blockSums[blockIdx.x] = sdata[255];
    unsigned int run = sdata[t] - s;
#pragma unroll
    for (int i = 0; i < 4; ++i) {
        int idx = base + t * 4 + i;
        if (idx < N) offsets[idx] = run;
        run += v[i];
    }
}

__global__ void scan2_kernel(unsigned int* __restrict__ blockSums, int nb) {
    __shared__ unsigned int sdata[1024];
    int t = threadIdx.x;
    unsigned int v = (t < nb) ? blockSums[t] : 0u;
    sdata[t] = v;
    __syncthreads();
    for (int off = 1; off < 1024; off <<= 1) {
        unsigned int x = (t >= off) ? sdata[t - off] : 0u;
        __syncthreads();
        sdata[t] += x;
        __syncthreads();
    }
    if (t < nb) blockSums[t] = sdata[t] - v;
}

__global__ void scan3_kernel(unsigned int* __restrict__ offsets,
                             const unsigned int* __restrict__ blockSums, int N) {
    int i = blockIdx.x * blockDim.x + threadIdx.x;
    if (i < N) offsets[i] += blockSums[i / SCAN_CHUNK];
}

// partial[s][r][lbin] := global start offset of slice s's segment of bin (r,lbin).
__global__ void pboff_kernel(unsigned int* __restrict__ partial,
                             const unsigned int* __restrict__ offsets,
                             int N, int nreg, int regsz) {
    int bin = blockIdx.x * blockDim.x + threadIdx.x;
    if (bin >= N) return;
    int r = bin / regsz;
    int lbin = bin - r * regsz;
    unsigned int base = offsets[bin];
    for (int s = 0; s < NSLICE; ++s) {
        size_t idx = (size_t)(s * nreg + r) * regsz + lbin;
        unsigned int cnt = partial[idx] >> 16;   // indeg count of this (slice,bin)
        partial[idx] = base;
        base += cnt;
    }
}

__global__ void transform_kernel(const float* __restrict__ feat, const float* __restrict__ weight,
                                 const float* __restrict__ wtype, const int* __restrict__ tinfo,
                                 const unsigned int* __restrict__ outdeg,
                                 unsigned short* __restrict__ h16, int N) {
    __shared__ float W[64 * 64];
    int t = threadIdx.x;
    const float4* w4 = (const float4*)weight;
    float4* W4 = (float4*)W;
#pragma unroll
    for (int i = 0; i < 4; ++i) W4[t + i * 256] = w4[t + i * 256];
    __syncthreads();

    int row = blockIdx.x * blockDim.x + t;
    if (row >= N) return;

    float s = rsqrtf(fmaxf((float)outdeg[row], 1.0f)) * wtype[tinfo[row]];

    float acc[64];
#pragma unroll
    for (int j = 0; j < 64; ++j) acc[j] = 0.0f;

    const float4* frow = (const float4*)(feat + (size_t)row * 64);
    for (int k4 = 0; k4 < 16; ++k4) {
        float4 a4 = frow[k4];
#pragma unroll
        for (int kk = 0; kk < 4; ++kk) {
            float a = (kk == 0) ? a4.x : (kk == 1) ? a4.y : (kk == 2) ? a4.z : a4.w;
            const float4* wr = (const float4*)&W[(k4 * 4 + kk) * 64];
#pragma unroll
            for (int j4 = 0; j4 < 16; ++j4) {
                float4 w = wr[j4];  // wave-uniform LDS address -> broadcast
                acc[j4 * 4 + 0] += a * w.x;
                acc[j4 * 4 + 1] += a * w.y;
                acc[j4 * 4 + 2] += a * w.z;
                acc[j4 * 4 + 3] += a * w.w;
            }
        }
    }

    unsigned int* hrow = (unsigned int*)(h16 + (size_t)row * 64);
#pragma unroll
    for (int j2 = 0; j2 < 32; ++j2) {
        unsigned int p = f2bf(acc[2 * j2] * s) | (f2bf(acc[2 * j2 + 1] * s) << 16);
        __builtin_nontemporal_store(p, hrow + j2);  // scalar u32: legal NT store
    }
}

// Zero global atomics: LDS cursors seeded with per-slice offsets; disjoint output ranges.
// Region r lands on XCD r (blockIdx % nreg, nreg==8): sorted_src slice stays XCD-local.
__global__ void bucket_lds_kernel(const int* __restrict__ src, const int* __restrict__ dst,
                                  const unsigned int* __restrict__ partial,
                                  int* __restrict__ sorted_src,
                                  int E, int nreg, int regsz, int chunk, int N) {
    __shared__ unsigned int cur[MAXREG];
    int r = blockIdx.x % nreg;
    int s = blockIdx.x / nreg;
    int lo = r * regsz;
    int hi = min(lo + regsz, N);
    int nb = hi - lo;
    int t = threadIdx.x;
    const unsigned int* pb = partial + (size_t)blockIdx.x * regsz;  // == (s*nreg+r)*regsz
    for (int b = t; b < nb; b += THREADS) cur[b] = pb[b];
    __syncthreads();

    int ebeg = s * chunk;
    int eend = min(E, ebeg + chunk);
    int main_end = ebeg + ((eend - ebeg) & ~3);
    for (int i = ebeg + t * 4; i + 4 <= main_end; i += THREADS * 4) {
        int4 d4 = *(const int4*)(dst + i);
        int4 s4 = *(const int4*)(src + i);
        if (d4.x >= lo && d4.x < hi) sorted_src[atomicAdd(&cur[d4.x - lo], 1u)] = s4.x;
        if (d4.y >= lo && d4.y < hi) sorted_src[atomicAdd(&cur[d4.y - lo], 1u)] = s4.y;
        if (d4.z >= lo && d4.z < hi) sorted_src[atomicAdd(&cur[d4.z - lo], 1u)] = s4.z;
        if (d4.w >= lo && d4.w < hi) sorted_src[atomicAdd(&cur[d4.w - lo], 1u)] = s4.w;
    }
    for (int i = main_end + t; i < eend; i += THREADS) {
        int d = dst[i];
        if (d >= lo && d < hi) sorted_src[atomicAdd(&cur[d - lo], 1u)] = src[i];
    }
}

// One wave per dst node. Lane l: half = l>>5 (edge parity), fp = l&31 (feature pair).
// One u32 load = 2 bf16 features of one edge; a wave-load covers 2 edges x 128B.
// XCD-affinity: team = blockIdx&7 handles node region team (matches bucket's writer XCD).
__global__ void gather_kernel(const int* __restrict__ sorted_src,
                              const unsigned int* __restrict__ offsets,
                              const unsigned int* __restrict__ indeg,
                              const unsigned short* __restrict__ h16,
                              const float* __restrict__ bias,
                              float* __restrict__ out, int N, int bpt) {
    int team = blockIdx.x & 7;
    int bidx = blockIdx.x >> 3;
    int vblock = team * bpt + bidx;
    int node = vblock * 4 + (threadIdx.x >> 6);
    if (node >= N) return;
    int lane = threadIdx.x & 63;
    int half = lane >> 5;
    int fp = lane & 31;

    unsigned int beg = offsets[node];
    unsigned int cnt = indeg[node];
    unsigned int end = beg + cnt;
    unsigned int i = beg;
    float ax = 0.0f, ay = 0.0f;

    for (; i + 8 <= end; i += 8) {
#pragma unroll
        for (int k = 0; k < 4; ++k) {
            unsigned int j = i + 2 * k + half;
            int sidx = sorted_src[j];
            unsigned int u = *(const unsigned int*)(h16 + ((size_t)sidx << 6) + (fp << 1));
            ax += __uint_as_float(u << 16);
            ay += __uint_as_float(u & 0xffff0000u);
        }
    }
    for (; i + 2 <= end; i += 2) {
        unsigned int j = i + half;
        int sidx = sorted_src[j];
        unsigned int u = *(const unsigned int*)(h16 + ((size_t)sidx << 6) + (fp << 1));
        ax += __uint_as_float(u << 16);
        ay += __uint_as_float(u & 0xffff0000u);
    }
    if (i < end) {  // odd tail: only lower half contributes
        int sidx = sorted_src[i];
        unsigned int u = *(const unsigned int*)(h16 + ((size_t)sidx << 6) + (fp << 1));
        if (half == 0) {
            ax += __uint_as_float(u << 16);
            ay += __uint_as_float(u & 0xffff0000u);
        }
    }

    ax += __shfl_xor(ax, 32, 64);
    ay += __shfl_xor(ay, 32, 64);

    if (half == 0) {
        float sc = rsqrtf(fmaxf((float)cnt, 1.0f));
        float2 b = *(const float2*)(bias + (fp << 1));
        float* op = out + ((size_t)node << 6) + (fp << 1);
        __builtin_nontemporal_store(ax * sc + b.x, op);
        __builtin_nontemporal_store(ay * sc + b.y, op + 1);
    }
}

extern "C" void kernel_launch(void* const* d_in, const int* in_sizes, int n_in,
                              void* d_out, int out_size, void* d_ws, size_t ws_size,
                              hipStream_t stream) {
    const float* feat   = (const float*)d_in[0];
    const float* weight = (const float*)d_in[1];
    const float* wtype  = (const float*)d_in[2];
    const float* bias   = (const float*)d_in[3];
    const int*   src    = (const int*)d_in[4];
    const int*   dst    = (const int*)d_in[5];
    const int*   tinfo  = (const int*)d_in[6];

    int E = in_sizes[4];
    int N = in_sizes[6];
    float* out = (float*)d_out;

    int nreg  = (N + MAXREG - 1) / MAXREG;               // 8 for N=100k
    int regsz = (N + nreg - 1) / nreg;                   // 12500
    int chunk = (((E + NSLICE - 1) / NSLICE) + 3) & ~3;  // 50000, mult of 4

    // Workspace: partial (12.8MB) | h16 (12.8MB) | outdeg | indeg | offsets | blockSums | sorted_src
    size_t partial_bytes = (size_t)NSLICE * nreg * regsz * sizeof(unsigned int);
    size_t h_bytes = (size_t)N * 64 * sizeof(unsigned short);

    char* ws = (char*)d_ws;
    unsigned int* partial   = (unsigned int*)ws;        ws += partial_bytes;
    unsigned short* h16     = (unsigned short*)ws;      ws += h_bytes;
    unsigned int* outdeg    = (unsigned int*)ws;        ws += (size_t)N * sizeof(unsigned int);
    unsigned int* indeg     = (unsigned int*)ws;        ws += (size_t)N * sizeof(unsigned int);
    unsigned int* offsets   = (unsigned int*)ws;        ws += (size_t)N * sizeof(unsigned int);
    unsigned int* blockSums = (unsigned int*)ws;        ws += 1024 * sizeof(unsigned int);
    int* sorted_src = (int*)ws;

    hist_kernel<<<NSLICE * nreg, THREADS, 0, stream>>>(src, dst, partial, E, nreg, regsz, chunk, N);
    reduce_kernel<<<(N + THREADS - 1) / THREADS, THREADS, 0, stream>>>(partial, outdeg, indeg, N, nreg, regsz);

    int nb = (N + SCAN_CHUNK - 1) / SCAN_CHUNK;
    scan1_kernel<<<nb, 256, 0, stream>>>(indeg, offsets, blockSums, N);
    scan2_kernel<<<1, 1024, 0, stream>>>(blockSums, nb);
    scan3_kernel<<<(N + THREADS - 1) / THREADS, THREADS, 0, stream>>>(offsets, blockSums, N);
    pboff_kernel<<<(N + THREADS - 1) / THREADS, THREADS, 0, stream>>>(partial, offsets, N, nreg, regsz);

    transform_kernel<<<(N + THREADS - 1) / THREADS, THREADS, 0, stream>>>(
        feat, weight, wtype, tinfo, outdeg, h16, N);

    bucket_lds_kernel<<<NSLICE * nreg, THREADS, 0, stream>>>(src, dst, partial, sorted_src, E, nreg, regsz, chunk, N);

    int node_blocks = (N + 3) / 4;           // 4 waves (nodes) per block
    int bpt = (node_blocks + 7) / 8;         // blocks per XCD team
    gather_kernel<<<bpt * 8, THREADS, 0, stream>>>(sorted_src, offsets, indeg, h16, bias, out, N, bpt);
}